// Round 1
// baseline (549.856 us; speedup 1.0000x reference)
//
#include <hip/hip_runtime.h>
#include <math.h>

#define L_SEQ 512
#define DM 768
#define DI 1536
#define DS 64
#define DC 4
#define DR 48
#define NXD 176  // DR + 2*DS

// ---------------------------------------------------------------------------
// LayerNorm: one block per row l (512 blocks x 256 threads)
// ---------------------------------------------------------------------------
__global__ __launch_bounds__(256) void ln_kernel(const float* __restrict__ x,
                                                 const float* __restrict__ w,
                                                 const float* __restrict__ b,
                                                 float* __restrict__ h) {
  int l = blockIdx.x;
  int tid = threadIdx.x;
  const float* xr = x + l * DM;
  float s = 0.f, s2 = 0.f;
  for (int i = tid; i < DM; i += 256) { float t = xr[i]; s += t; s2 += t * t; }
#pragma unroll
  for (int off = 32; off; off >>= 1) { s += __shfl_xor(s, off); s2 += __shfl_xor(s2, off); }
  __shared__ float ls[4], ls2[4];
  int wid = tid >> 6, lane = tid & 63;
  if (lane == 0) { ls[wid] = s; ls2[wid] = s2; }
  __syncthreads();
  s = ls[0] + ls[1] + ls[2] + ls[3];
  s2 = ls2[0] + ls2[1] + ls2[2] + ls2[3];
  float mean = s * (1.f / DM);
  float var = s2 * (1.f / DM) - mean * mean;
  float rstd = rsqrtf(var + 1e-5f);
  for (int i = tid; i < DM; i += 256)
    h[l * DM + i] = (xr[i] - mean) * rstd * w[i] + b[i];
}

// ---------------------------------------------------------------------------
// f32 tiled GEMM: C[M,N] = A[M,K] . B[N,K]^T  (dot of rows)
// 64x64 tile, 256 threads, each thread a 4x4 micro-tile.
// LDS stored transposed [BK][BM+4] so inner loop uses float4 LDS reads.
// Split-K via gridDim.z: each z-slice writes a partial C to Cpart + z*M*N.
// Requires: M % 64 == 0, K % (16*gridDim.z) == 0. N is bounds-checked.
// ---------------------------------------------------------------------------
#define BM 64
#define BN 64
#define BK 16
#define LDT 68  // BM + 4 padding (bank-conflict break)

__global__ __launch_bounds__(256) void gemm_tiled(const float* __restrict__ A,
                                                  const float* __restrict__ B,
                                                  float* __restrict__ Cpart,
                                                  int M, int N, int K) {
  __shared__ float As[BK][LDT];
  __shared__ float Bs[BK][LDT];
  int tid = threadIdx.x;
  int tx = tid & 15, ty = tid >> 4;
  int bm = blockIdx.y * BM, bn = blockIdx.x * BN;
  int lr = tid >> 2;          // 0..63: tile row for loading
  int lc = (tid & 3) << 2;    // 0,4,8,12: k-offset for loading (float4)
  int kchunk = K / gridDim.z;
  int kbeg = blockIdx.z * kchunk;
  float* C = Cpart + (size_t)blockIdx.z * (size_t)M * (size_t)N;
  float acc[4][4] = {{0.f, 0.f, 0.f, 0.f}, {0.f, 0.f, 0.f, 0.f},
                     {0.f, 0.f, 0.f, 0.f}, {0.f, 0.f, 0.f, 0.f}};
  for (int k0 = kbeg; k0 < kbeg + kchunk; k0 += BK) {
    float4 va = *(const float4*)(A + (size_t)(bm + lr) * K + k0 + lc);
    float4 vb = make_float4(0.f, 0.f, 0.f, 0.f);
    int nrow = bn + lr;
    if (nrow < N) vb = *(const float4*)(B + (size_t)nrow * K + k0 + lc);
    As[lc + 0][lr] = va.x; As[lc + 1][lr] = va.y;
    As[lc + 2][lr] = va.z; As[lc + 3][lr] = va.w;
    Bs[lc + 0][lr] = vb.x; Bs[lc + 1][lr] = vb.y;
    Bs[lc + 2][lr] = vb.z; Bs[lc + 3][lr] = vb.w;
    __syncthreads();
#pragma unroll
    for (int kk = 0; kk < BK; ++kk) {
      float4 a = *(const float4*)&As[kk][ty << 2];
      float4 b = *(const float4*)&Bs[kk][tx << 2];
      float av[4] = {a.x, a.y, a.z, a.w};
      float bv[4] = {b.x, b.y, b.z, b.w};
#pragma unroll
      for (int i = 0; i < 4; ++i)
#pragma unroll
        for (int j = 0; j < 4; ++j)
          acc[i][j] = fmaf(av[i], bv[j], acc[i][j]);
    }
    __syncthreads();
  }
#pragma unroll
  for (int i = 0; i < 4; ++i) {
    int m = bm + (ty << 2) + i;
#pragma unroll
    for (int j = 0; j < 4; ++j) {
      int n = bn + (tx << 2) + j;
      if (n < N) C[(size_t)m * N + n] = acc[i][j];
    }
  }
}

// ---------------------------------------------------------------------------
// Split-K reduce: out[i] = (res ? res[i] : 0) + sum_z part[z*MN + i]
// ---------------------------------------------------------------------------
__global__ __launch_bounds__(256) void reduce_add(const float* __restrict__ part,
                                                  int MN, int splitk,
                                                  const float* __restrict__ res,
                                                  float* __restrict__ out) {
  int i = blockIdx.x * 256 + threadIdx.x;
  if (i >= MN) return;
  float a = res ? res[i] : 0.f;
  for (int z = 0; z < splitk; ++z) a += part[(size_t)z * MN + i];
  out[i] = a;
}

// ---------------------------------------------------------------------------
// Causal depthwise conv (window 4) + bias + SiLU.
// x_in lives in xz[l*2*DI + d] (d < DI). One thread per (l,d).
// ---------------------------------------------------------------------------
__global__ __launch_bounds__(256) void conv_silu_kernel(const float* __restrict__ xz,
                                                        const float* __restrict__ cw,
                                                        const float* __restrict__ cb,
                                                        float* __restrict__ xc) {
  int idx = blockIdx.x * 256 + threadIdx.x;
  if (idx >= L_SEQ * DI) return;
  int l = idx / DI, d = idx - l * DI;
  float acc = cb[d];
#pragma unroll
  for (int j = 0; j < DC; ++j) {
    int ll = l - (DC - 1) + j;
    if (ll >= 0) acc = fmaf(xz[(size_t)ll * (2 * DI) + d], cw[d * DC + j], acc);
  }
  float sig = 1.f / (1.f + __expf(-acc));
  xc[idx] = acc * sig;
}

// ---------------------------------------------------------------------------
// dt = softplus(x_dbl[:, :DR] @ dt_proj_w^T + dt_proj_b). Thread per (l,d).
// ---------------------------------------------------------------------------
__global__ __launch_bounds__(256) void dtproj_kernel(const float* __restrict__ xdbl,
                                                     const float* __restrict__ w,
                                                     const float* __restrict__ bias,
                                                     float* __restrict__ dt) {
  int idx = blockIdx.x * 256 + threadIdx.x;
  if (idx >= L_SEQ * DI) return;
  int l = idx / DI, d = idx - l * DI;
  const float* xr = xdbl + (size_t)l * NXD;   // wave-uniform (block spans one l)
  const float* wr = w + (size_t)d * DR;
  float acc = bias[d];
#pragma unroll 8
  for (int r = 0; r < DR; ++r) acc = fmaf(xr[r], wr[r], acc);
  dt[idx] = (acc > 20.f) ? acc : log1pf(__expf(acc));
}

// ---------------------------------------------------------------------------
// Selective scan, fused with +x*D and *silu(z).
// One wave per channel d; lane = state index n (0..63).
// s_{l} = exp(dt_l * A_n) * s_{l-1} + dt_l * x_l * B_{l,n}
// y_{l,d} = sum_n s * C_{l,n}; then (+x*D) * silu(z).
// Global loads for step l+1 issued before computing step l (SW pipeline).
// ---------------------------------------------------------------------------
__global__ __launch_bounds__(256) void scan_kernel(const float* __restrict__ dt,
                                                   const float* __restrict__ xc,
                                                   const float* __restrict__ xdbl,
                                                   const float* __restrict__ A_log,
                                                   const float* __restrict__ Dv,
                                                   const float* __restrict__ xz,
                                                   float* __restrict__ y) {
  int lane = threadIdx.x & 63;
  int wid = threadIdx.x >> 6;
  int d = blockIdx.x * 4 + wid;
  float A = -__expf(A_log[(size_t)d * DS + lane]);
  float Dd = Dv[d];
  float s = 0.f;
  // prefetch l = 0
  float dtl = dt[d];
  float xl = xc[d];
  float Bn = xdbl[DR + lane];
  float Cn = xdbl[DR + DS + lane];
  for (int l = 0; l < L_SEQ; ++l) {
    float dt_c = dtl, x_c = xl, B_c = Bn, C_c = Cn;
    if (l < L_SEQ - 1) {
      size_t r = (size_t)(l + 1);
      dtl = dt[r * DI + d];
      xl = xc[r * DI + d];
      Bn = xdbl[r * NXD + DR + lane];
      Cn = xdbl[r * NXD + DR + DS + lane];
    }
    float dA = __expf(dt_c * A);
    s = fmaf(dA, s, dt_c * x_c * B_c);
    float p = s * C_c;
#pragma unroll
    for (int off = 32; off; off >>= 1) p += __shfl_xor(p, off);
    if (lane == 0) {
      float zv = xz[(size_t)l * (2 * DI) + DI + d];
      float sig = 1.f / (1.f + __expf(-zv));
      y[(size_t)l * DI + d] = (p + x_c * Dd) * (zv * sig);
    }
  }
}

// ---------------------------------------------------------------------------
// Launcher
// ---------------------------------------------------------------------------
extern "C" void kernel_launch(void* const* d_in, const int* in_sizes, int n_in,
                              void* d_out, int out_size, void* d_ws, size_t ws_size,
                              hipStream_t stream) {
  const float* x         = (const float*)d_in[0];
  const float* ln_w      = (const float*)d_in[1];
  const float* ln_b      = (const float*)d_in[2];
  const float* in_proj_w = (const float*)d_in[3];   // [3072, 768]
  const float* conv_w    = (const float*)d_in[4];   // [1536, 1, 4]
  const float* conv_b    = (const float*)d_in[5];
  const float* x_proj_w  = (const float*)d_in[6];   // [176, 1536]
  const float* dt_proj_w = (const float*)d_in[7];   // [1536, 48]
  const float* dt_proj_b = (const float*)d_in[8];
  const float* A_log     = (const float*)d_in[9];   // [1536, 64]
  const float* Dv        = (const float*)d_in[10];
  const float* out_proj_w= (const float*)d_in[11];  // [768, 1536]
  float* out = (float*)d_out;

  float* ws = (float*)d_ws;
  float* h     = ws;                       // 512*768   = 393216
  float* xz    = h + 393216;               // 512*3072  = 1572864
  float* xconv = xz + 1572864;             // 512*1536  = 786432
  float* xdbl  = xconv + 786432;           // 512*176   = 90112
  float* dtb   = xdbl + 90112;             // 512*1536  = 786432
  float* yb    = dtb + 786432;             // 512*1536  = 786432
  float* part2 = yb + 786432;              // 8*512*176 = 720896
  float* part3 = part2 + 720896;           // 4*512*768 = 1572864

  // 1. LayerNorm
  ln_kernel<<<L_SEQ, 256, 0, stream>>>(x, ln_w, ln_b, h);

  // 2. in_proj: xz[512,3072] = h[512,768] . in_proj_w[3072,768]^T
  gemm_tiled<<<dim3(3072 / BN, L_SEQ / BM, 1), 256, 0, stream>>>(
      h, in_proj_w, xz, L_SEQ, 2 * DI, DM);

  // 3. causal depthwise conv + SiLU
  conv_silu_kernel<<<(L_SEQ * DI) / 256, 256, 0, stream>>>(xz, conv_w, conv_b, xconv);

  // 4. x_proj: xdbl[512,176] = xconv . x_proj_w^T  (split-K = 8)
  gemm_tiled<<<dim3((NXD + BN - 1) / BN, L_SEQ / BM, 8), 256, 0, stream>>>(
      xconv, x_proj_w, part2, L_SEQ, NXD, DI);
  reduce_add<<<(L_SEQ * NXD + 255) / 256, 256, 0, stream>>>(
      part2, L_SEQ * NXD, 8, nullptr, xdbl);

  // 5. dt_proj + softplus
  dtproj_kernel<<<(L_SEQ * DI) / 256, 256, 0, stream>>>(xdbl, dt_proj_w, dt_proj_b, dtb);

  // 6. selective scan (fused +x*D and *silu(z))
  scan_kernel<<<DI / 4, 256, 0, stream>>>(dtb, xconv, xdbl, A_log, Dv, xz, yb);

  // 7. out_proj + residual: out = x + yb . out_proj_w^T  (split-K = 4)
  gemm_tiled<<<dim3(DM / BN, L_SEQ / BM, 4), 256, 0, stream>>>(
      yb, out_proj_w, part3, L_SEQ, DM, DI);
  reduce_add<<<(L_SEQ * DM + 255) / 256, 256, 0, stream>>>(
      part3, L_SEQ * DM, 4, x, out);
}

// Round 2
// 326.685 us; speedup vs baseline: 1.6831x; 1.6831x over previous
//
#include <hip/hip_runtime.h>
#include <math.h>

#define L_SEQ 512
#define DM 768
#define DI 1536
#define DS 64
#define DC 4
#define DR 48
#define NXD 176  // DR + 2*DS
#define NC 8     // time chunks
#define TC 64    // steps per chunk (L_SEQ/NC)

// ---------------------------------------------------------------------------
// LayerNorm: one block per row l
// ---------------------------------------------------------------------------
__global__ __launch_bounds__(256) void ln_kernel(const float* __restrict__ x,
                                                 const float* __restrict__ w,
                                                 const float* __restrict__ b,
                                                 float* __restrict__ h) {
  int l = blockIdx.x;
  int tid = threadIdx.x;
  const float* xr = x + l * DM;
  float s = 0.f, s2 = 0.f;
  for (int i = tid; i < DM; i += 256) { float t = xr[i]; s += t; s2 += t * t; }
#pragma unroll
  for (int off = 32; off; off >>= 1) { s += __shfl_xor(s, off); s2 += __shfl_xor(s2, off); }
  __shared__ float ls[4], ls2[4];
  int wid = tid >> 6, lane = tid & 63;
  if (lane == 0) { ls[wid] = s; ls2[wid] = s2; }
  __syncthreads();
  s = ls[0] + ls[1] + ls[2] + ls[3];
  s2 = ls2[0] + ls2[1] + ls2[2] + ls2[3];
  float mean = s * (1.f / DM);
  float var = s2 * (1.f / DM) - mean * mean;
  float rstd = rsqrtf(var + 1e-5f);
  for (int i = tid; i < DM; i += 256)
    h[l * DM + i] = (xr[i] - mean) * rstd * w[i] + b[i];
}

// ---------------------------------------------------------------------------
// f32 tiled GEMM: C[M,N] = A[M,K] . B[N,K]^T ; split-K partials via gridDim.z
// ---------------------------------------------------------------------------
#define BM 64
#define BN 64
#define BK 16
#define LDT 68

__global__ __launch_bounds__(256) void gemm_tiled(const float* __restrict__ A,
                                                  const float* __restrict__ B,
                                                  float* __restrict__ Cpart,
                                                  int M, int N, int K) {
  __shared__ float As[BK][LDT];
  __shared__ float Bs[BK][LDT];
  int tid = threadIdx.x;
  int tx = tid & 15, ty = tid >> 4;
  int bm = blockIdx.y * BM, bn = blockIdx.x * BN;
  int lr = tid >> 2;
  int lc = (tid & 3) << 2;
  int kchunk = K / gridDim.z;
  int kbeg = blockIdx.z * kchunk;
  float* C = Cpart + (size_t)blockIdx.z * (size_t)M * (size_t)N;
  float acc[4][4] = {{0.f, 0.f, 0.f, 0.f}, {0.f, 0.f, 0.f, 0.f},
                     {0.f, 0.f, 0.f, 0.f}, {0.f, 0.f, 0.f, 0.f}};
  for (int k0 = kbeg; k0 < kbeg + kchunk; k0 += BK) {
    float4 va = *(const float4*)(A + (size_t)(bm + lr) * K + k0 + lc);
    float4 vb = make_float4(0.f, 0.f, 0.f, 0.f);
    int nrow = bn + lr;
    if (nrow < N) vb = *(const float4*)(B + (size_t)nrow * K + k0 + lc);
    As[lc + 0][lr] = va.x; As[lc + 1][lr] = va.y;
    As[lc + 2][lr] = va.z; As[lc + 3][lr] = va.w;
    Bs[lc + 0][lr] = vb.x; Bs[lc + 1][lr] = vb.y;
    Bs[lc + 2][lr] = vb.z; Bs[lc + 3][lr] = vb.w;
    __syncthreads();
#pragma unroll
    for (int kk = 0; kk < BK; ++kk) {
      float4 a = *(const float4*)&As[kk][ty << 2];
      float4 b = *(const float4*)&Bs[kk][tx << 2];
      float av[4] = {a.x, a.y, a.z, a.w};
      float bv[4] = {b.x, b.y, b.z, b.w};
#pragma unroll
      for (int i = 0; i < 4; ++i)
#pragma unroll
        for (int j = 0; j < 4; ++j)
          acc[i][j] = fmaf(av[i], bv[j], acc[i][j]);
    }
    __syncthreads();
  }
#pragma unroll
  for (int i = 0; i < 4; ++i) {
    int m = bm + (ty << 2) + i;
#pragma unroll
    for (int j = 0; j < 4; ++j) {
      int n = bn + (tx << 2) + j;
      if (n < N) C[(size_t)m * N + n] = acc[i][j];
    }
  }
}

__global__ __launch_bounds__(256) void reduce_add(const float* __restrict__ part,
                                                  int MN, int splitk,
                                                  const float* __restrict__ res,
                                                  float* __restrict__ out) {
  int i = blockIdx.x * 256 + threadIdx.x;
  if (i >= MN) return;
  float a = res ? res[i] : 0.f;
  for (int z = 0; z < splitk; ++z) a += part[(size_t)z * MN + i];
  out[i] = a;
}

// ---------------------------------------------------------------------------
// Causal depthwise conv (window 4) + bias + SiLU
// ---------------------------------------------------------------------------
__global__ __launch_bounds__(256) void conv_silu_kernel(const float* __restrict__ xz,
                                                        const float* __restrict__ cw,
                                                        const float* __restrict__ cb,
                                                        float* __restrict__ xc) {
  int idx = blockIdx.x * 256 + threadIdx.x;
  if (idx >= L_SEQ * DI) return;
  int l = idx / DI, d = idx - l * DI;
  float acc = cb[d];
#pragma unroll
  for (int j = 0; j < DC; ++j) {
    int ll = l - (DC - 1) + j;
    if (ll >= 0) acc = fmaf(xz[(size_t)ll * (2 * DI) + d], cw[d * DC + j], acc);
  }
  float sig = 1.f / (1.f + __expf(-acc));
  xc[idx] = acc * sig;
}

// ---------------------------------------------------------------------------
// dt = softplus(x_dbl[:, :DR] @ dt_proj_w^T + dt_proj_b)
// ---------------------------------------------------------------------------
__global__ __launch_bounds__(256) void dtproj_kernel(const float* __restrict__ xdbl,
                                                     const float* __restrict__ w,
                                                     const float* __restrict__ bias,
                                                     float* __restrict__ dt) {
  int idx = blockIdx.x * 256 + threadIdx.x;
  if (idx >= L_SEQ * DI) return;
  int l = idx / DI, d = idx - l * DI;
  const float* xr = xdbl + (size_t)l * NXD;
  const float* wr = w + (size_t)d * DR;
  float acc = bias[d];
#pragma unroll 8
  for (int r = 0; r < DR; ++r) acc = fmaf(xr[r], wr[r], acc);
  dt[idx] = (acc > 20.f) ? acc : log1pf(__expf(acc));
}

// ---------------------------------------------------------------------------
// Chunked selective scan.
// Pass 1: per (chunk c, channel d) wave, run local recurrence from s=0 over
//         TC steps; emit end state send[c,d,n] and dt-sum dts[c,d]
//         (prod of exp(dt*A) over chunk == exp(A * sum dt)). Chunks 0..NC-2.
// ---------------------------------------------------------------------------
__global__ __launch_bounds__(256) void scan_p1(const float* __restrict__ dt,
                                               const float* __restrict__ xc,
                                               const float* __restrict__ xdbl,
                                               const float* __restrict__ A_log,
                                               float* __restrict__ send,
                                               float* __restrict__ dts) {
  int lane = threadIdx.x & 63;
  int wid = threadIdx.x >> 6;
  int pair = blockIdx.x * 4 + wid;   // [0, (NC-1)*DI)
  int c = pair / DI;
  int d = pair - c * DI;
  float A = -__expf(A_log[(size_t)d * DS + lane]);
  float s = 0.f, dsum = 0.f;
  int l0 = c * TC;
  float dtl = dt[(size_t)l0 * DI + d];
  float xl  = xc[(size_t)l0 * DI + d];
  float Bn  = xdbl[(size_t)l0 * NXD + DR + lane];
  for (int t = 0; t < TC; ++t) {
    float dt_c = dtl, x_c = xl, B_c = Bn;
    if (t < TC - 1) {
      size_t r = (size_t)(l0 + t + 1);
      dtl = dt[r * DI + d];
      xl  = xc[r * DI + d];
      Bn  = xdbl[r * NXD + DR + lane];
    }
    dsum += dt_c;
    float dA = __expf(dt_c * A);
    s = fmaf(dA, s, dt_c * x_c * B_c);
  }
  send[((size_t)c * DI + d) * DS + lane] = s;
  if (lane == 0) dts[c * DI + d] = dsum;
}

// ---------------------------------------------------------------------------
// Pass 2: prefix over chunks. s_init[c] = exp(A*dts[c-1])*s_init[c-1]+send[c-1]
// ---------------------------------------------------------------------------
__global__ __launch_bounds__(256) void scan_p2(const float* __restrict__ send,
                                               const float* __restrict__ dts,
                                               const float* __restrict__ A_log,
                                               float* __restrict__ sinit) {
  int lane = threadIdx.x & 63;
  int wid = threadIdx.x >> 6;
  int d = blockIdx.x * 4 + wid;
  float A = -__expf(A_log[(size_t)d * DS + lane]);
  float s = 0.f;
  for (int c = 1; c < NC; ++c) {
    float P = __expf(A * dts[(c - 1) * DI + d]);
    s = fmaf(P, s, send[((size_t)(c - 1) * DI + d) * DS + lane]);
    sinit[((size_t)c * DI + d) * DS + lane] = s;
  }
}

// ---------------------------------------------------------------------------
// Pass 3: re-run each chunk from its correct initial state, compute
// y = (sum_n s*C + x*D) * silu(z).  12288 waves -> ~12 waves/SIMD, the
// butterfly-chain latency is hidden by TLP.
// ---------------------------------------------------------------------------
__global__ __launch_bounds__(256) void scan_p3(const float* __restrict__ dt,
                                               const float* __restrict__ xc,
                                               const float* __restrict__ xdbl,
                                               const float* __restrict__ A_log,
                                               const float* __restrict__ Dv,
                                               const float* __restrict__ xz,
                                               const float* __restrict__ sinit,
                                               float* __restrict__ y) {
  int lane = threadIdx.x & 63;
  int wid = threadIdx.x >> 6;
  int pair = blockIdx.x * 4 + wid;   // [0, NC*DI)
  int c = pair / DI;
  int d = pair - c * DI;
  float A = -__expf(A_log[(size_t)d * DS + lane]);
  float Dd = Dv[d];
  float s = (c == 0) ? 0.f : sinit[((size_t)c * DI + d) * DS + lane];
  int l0 = c * TC;
  float dtl = dt[(size_t)l0 * DI + d];
  float xl  = xc[(size_t)l0 * DI + d];
  float Bn  = xdbl[(size_t)l0 * NXD + DR + lane];
  float Cn  = xdbl[(size_t)l0 * NXD + DR + DS + lane];
  for (int t = 0; t < TC; ++t) {
    int l = l0 + t;
    float dt_c = dtl, x_c = xl, B_c = Bn, C_c = Cn;
    if (t < TC - 1) {
      size_t r = (size_t)(l + 1);
      dtl = dt[r * DI + d];
      xl  = xc[r * DI + d];
      Bn  = xdbl[r * NXD + DR + lane];
      Cn  = xdbl[r * NXD + DR + DS + lane];
    }
    float dA = __expf(dt_c * A);
    s = fmaf(dA, s, dt_c * x_c * B_c);
    float p = s * C_c;
#pragma unroll
    for (int off = 32; off; off >>= 1) p += __shfl_xor(p, off);
    if (lane == 0) {
      float zv = xz[(size_t)l * (2 * DI) + DI + d];
      float sig = 1.f / (1.f + __expf(-zv));
      y[(size_t)l * DI + d] = (p + x_c * Dd) * (zv * sig);
    }
  }
}

// ---------------------------------------------------------------------------
// Launcher. Workspace aliased by lifetime: region R is reused sequentially by
// part1 (in_proj partials) -> part2 (x_proj partials) -> send/dts/sinit ->
// part3 (out_proj partials). All uses are ordered on the same stream.
// ---------------------------------------------------------------------------
extern "C" void kernel_launch(void* const* d_in, const int* in_sizes, int n_in,
                              void* d_out, int out_size, void* d_ws, size_t ws_size,
                              hipStream_t stream) {
  const float* x         = (const float*)d_in[0];
  const float* ln_w      = (const float*)d_in[1];
  const float* ln_b      = (const float*)d_in[2];
  const float* in_proj_w = (const float*)d_in[3];
  const float* conv_w    = (const float*)d_in[4];
  const float* conv_b    = (const float*)d_in[5];
  const float* x_proj_w  = (const float*)d_in[6];
  const float* dt_proj_w = (const float*)d_in[7];
  const float* dt_proj_b = (const float*)d_in[8];
  const float* A_log     = (const float*)d_in[9];
  const float* Dv        = (const float*)d_in[10];
  const float* out_proj_w= (const float*)d_in[11];
  float* out = (float*)d_out;

  float* ws = (float*)d_ws;
  float* h     = ws;                        // 393216
  float* xz    = h + 393216;                // 1572864
  float* xconv = xz + 1572864;              // 786432
  float* xdbl  = xconv + 786432;            // 90112
  float* dtb   = xdbl + 90112;              // 786432
  float* yb    = dtb + 786432;              // 786432
  float* R     = yb + 786432;               // 3145728 shared region
  float* part1 = R;                         // 2*512*3072 = 3145728
  float* part2 = R;                         // 16*512*176 = 1441792
  float* send  = R;                         // 7*1536*64  = 688128
  float* dts   = R + 688128;                // 7*1536     = 10752
  float* sinit = R + 698880;                // 8*1536*64  = 786432
  float* part3 = R;                         // 8*512*768  = 3145728

  // 1. LayerNorm
  ln_kernel<<<L_SEQ, 256, 0, stream>>>(x, ln_w, ln_b, h);

  // 2. in_proj (split-K 2)
  gemm_tiled<<<dim3(3072 / BN, L_SEQ / BM, 2), 256, 0, stream>>>(
      h, in_proj_w, part1, L_SEQ, 2 * DI, DM);
  reduce_add<<<(L_SEQ * 2 * DI + 255) / 256, 256, 0, stream>>>(
      part1, L_SEQ * 2 * DI, 2, nullptr, xz);

  // 3. causal depthwise conv + SiLU
  conv_silu_kernel<<<(L_SEQ * DI) / 256, 256, 0, stream>>>(xz, conv_w, conv_b, xconv);

  // 4. x_proj (split-K 16)
  gemm_tiled<<<dim3((NXD + BN - 1) / BN, L_SEQ / BM, 16), 256, 0, stream>>>(
      xconv, x_proj_w, part2, L_SEQ, NXD, DI);
  reduce_add<<<(L_SEQ * NXD + 255) / 256, 256, 0, stream>>>(
      part2, L_SEQ * NXD, 16, nullptr, xdbl);

  // 5. dt_proj + softplus
  dtproj_kernel<<<(L_SEQ * DI) / 256, 256, 0, stream>>>(xdbl, dt_proj_w, dt_proj_b, dtb);

  // 6. chunked selective scan
  scan_p1<<<((NC - 1) * DI) / 4, 256, 0, stream>>>(dtb, xconv, xdbl, A_log, send, dts);
  scan_p2<<<DI / 4, 256, 0, stream>>>(send, dts, A_log, sinit);
  scan_p3<<<(NC * DI) / 4, 256, 0, stream>>>(dtb, xconv, xdbl, A_log, Dv, xz, sinit, yb);

  // 7. out_proj + residual (split-K 8)
  gemm_tiled<<<dim3(DM / BN, L_SEQ / BM, 8), 256, 0, stream>>>(
      yb, out_proj_w, part3, L_SEQ, DM, DI);
  reduce_add<<<(L_SEQ * DM + 255) / 256, 256, 0, stream>>>(
      part3, L_SEQ * DM, 8, x, out);
}

// Round 3
// 280.773 us; speedup vs baseline: 1.9584x; 1.1635x over previous
//
#include <hip/hip_runtime.h>
#include <math.h>

#define L_SEQ 512
#define DM 768
#define DI 1536
#define DS 64
#define DC 4
#define DR 48
#define NXD 176  // DR + 2*DS
#define NC 8     // time chunks
#define TC 64    // steps per chunk (L_SEQ/NC)

// ---------------------------------------------------------------------------
// Cross-lane helpers
// ---------------------------------------------------------------------------
__device__ __forceinline__ float bp_add(float p, int addr) {
  return p + __int_as_float(__builtin_amdgcn_ds_bpermute(addr, __float_as_int(p)));
}
__device__ __forceinline__ float lane_read(float v, int t) {
  return __int_as_float(__builtin_amdgcn_readlane(__float_as_int(v), t));
}

// ---------------------------------------------------------------------------
// LayerNorm: one block per row l
// ---------------------------------------------------------------------------
__global__ __launch_bounds__(256) void ln_kernel(const float* __restrict__ x,
                                                 const float* __restrict__ w,
                                                 const float* __restrict__ b,
                                                 float* __restrict__ h) {
  int l = blockIdx.x;
  int tid = threadIdx.x;
  const float* xr = x + l * DM;
  float s = 0.f, s2 = 0.f;
  for (int i = tid; i < DM; i += 256) { float t = xr[i]; s += t; s2 += t * t; }
#pragma unroll
  for (int off = 32; off; off >>= 1) { s += __shfl_xor(s, off); s2 += __shfl_xor(s2, off); }
  __shared__ float ls[4], ls2[4];
  int wid = tid >> 6, lane = tid & 63;
  if (lane == 0) { ls[wid] = s; ls2[wid] = s2; }
  __syncthreads();
  s = ls[0] + ls[1] + ls[2] + ls[3];
  s2 = ls2[0] + ls2[1] + ls2[2] + ls2[3];
  float mean = s * (1.f / DM);
  float var = s2 * (1.f / DM) - mean * mean;
  float rstd = rsqrtf(var + 1e-5f);
  for (int i = tid; i < DM; i += 256)
    h[l * DM + i] = (xr[i] - mean) * rstd * w[i] + b[i];
}

// ---------------------------------------------------------------------------
// f32 tiled GEMM: C[M,N] = A[M,K] . B[N,K]^T ; split-K partials via gridDim.z
// ---------------------------------------------------------------------------
#define BM 64
#define BN 64
#define BK 16
#define LDT 68

__global__ __launch_bounds__(256) void gemm_tiled(const float* __restrict__ A,
                                                  const float* __restrict__ B,
                                                  float* __restrict__ Cpart,
                                                  int M, int N, int K) {
  __shared__ float As[BK][LDT];
  __shared__ float Bs[BK][LDT];
  int tid = threadIdx.x;
  int tx = tid & 15, ty = tid >> 4;
  int bm = blockIdx.y * BM, bn = blockIdx.x * BN;
  int lr = tid >> 2;
  int lc = (tid & 3) << 2;
  int kchunk = K / gridDim.z;
  int kbeg = blockIdx.z * kchunk;
  float* C = Cpart + (size_t)blockIdx.z * (size_t)M * (size_t)N;
  float acc[4][4] = {{0.f, 0.f, 0.f, 0.f}, {0.f, 0.f, 0.f, 0.f},
                     {0.f, 0.f, 0.f, 0.f}, {0.f, 0.f, 0.f, 0.f}};
  for (int k0 = kbeg; k0 < kbeg + kchunk; k0 += BK) {
    float4 va = *(const float4*)(A + (size_t)(bm + lr) * K + k0 + lc);
    float4 vb = make_float4(0.f, 0.f, 0.f, 0.f);
    int nrow = bn + lr;
    if (nrow < N) vb = *(const float4*)(B + (size_t)nrow * K + k0 + lc);
    As[lc + 0][lr] = va.x; As[lc + 1][lr] = va.y;
    As[lc + 2][lr] = va.z; As[lc + 3][lr] = va.w;
    Bs[lc + 0][lr] = vb.x; Bs[lc + 1][lr] = vb.y;
    Bs[lc + 2][lr] = vb.z; Bs[lc + 3][lr] = vb.w;
    __syncthreads();
#pragma unroll
    for (int kk = 0; kk < BK; ++kk) {
      float4 a = *(const float4*)&As[kk][ty << 2];
      float4 b = *(const float4*)&Bs[kk][tx << 2];
      float av[4] = {a.x, a.y, a.z, a.w};
      float bv[4] = {b.x, b.y, b.z, b.w};
#pragma unroll
      for (int i = 0; i < 4; ++i)
#pragma unroll
        for (int j = 0; j < 4; ++j)
          acc[i][j] = fmaf(av[i], bv[j], acc[i][j]);
    }
    __syncthreads();
  }
#pragma unroll
  for (int i = 0; i < 4; ++i) {
    int m = bm + (ty << 2) + i;
#pragma unroll
    for (int j = 0; j < 4; ++j) {
      int n = bn + (tx << 2) + j;
      if (n < N) C[(size_t)m * N + n] = acc[i][j];
    }
  }
}

__global__ __launch_bounds__(256) void reduce_add(const float* __restrict__ part,
                                                  int MN, int splitk,
                                                  const float* __restrict__ res,
                                                  float* __restrict__ out) {
  int i = blockIdx.x * 256 + threadIdx.x;
  if (i >= MN) return;
  float a = res ? res[i] : 0.f;
  for (int z = 0; z < splitk; ++z) a += part[(size_t)z * MN + i];
  out[i] = a;
}

// ---------------------------------------------------------------------------
// Causal depthwise conv (window 4) + bias + SiLU
// ---------------------------------------------------------------------------
__global__ __launch_bounds__(256) void conv_silu_kernel(const float* __restrict__ xz,
                                                        const float* __restrict__ cw,
                                                        const float* __restrict__ cb,
                                                        float* __restrict__ xc) {
  int idx = blockIdx.x * 256 + threadIdx.x;
  if (idx >= L_SEQ * DI) return;
  int l = idx / DI, d = idx - l * DI;
  float acc = cb[d];
#pragma unroll
  for (int j = 0; j < DC; ++j) {
    int ll = l - (DC - 1) + j;
    if (ll >= 0) acc = fmaf(xz[(size_t)ll * (2 * DI) + d], cw[d * DC + j], acc);
  }
  float sig = 1.f / (1.f + __expf(-acc));
  xc[idx] = acc * sig;
}

// ---------------------------------------------------------------------------
// dt = softplus(x_dbl[:, :DR] @ dt_proj_w^T + dt_proj_b)
// ---------------------------------------------------------------------------
__global__ __launch_bounds__(256) void dtproj_kernel(const float* __restrict__ xdbl,
                                                     const float* __restrict__ w,
                                                     const float* __restrict__ bias,
                                                     float* __restrict__ dt) {
  int idx = blockIdx.x * 256 + threadIdx.x;
  if (idx >= L_SEQ * DI) return;
  int l = idx / DI, d = idx - l * DI;
  const float* xr = xdbl + (size_t)l * NXD;
  const float* wr = w + (size_t)d * DR;
  float acc = bias[d];
#pragma unroll 8
  for (int r = 0; r < DR; ++r) acc = fmaf(xr[r], wr[r], acc);
  dt[idx] = (acc > 20.f) ? acc : log1pf(__expf(acc));
}

// ---------------------------------------------------------------------------
// Chunked selective scan, pass 1 (chunks 0..NC-2): local recurrence from 0.
// Lane t preloads dt/x for step t; per-step broadcast via v_readlane (no
// memory, no addr math). B via single incremented pointer.
// ---------------------------------------------------------------------------
__global__ __launch_bounds__(256) void scan_p1(const float* __restrict__ dt,
                                               const float* __restrict__ xc,
                                               const float* __restrict__ xdbl,
                                               const float* __restrict__ A_log,
                                               float* __restrict__ send,
                                               float* __restrict__ dts) {
  int lane = threadIdx.x & 63;
  int wid = threadIdx.x >> 6;
  int pair = blockIdx.x * 4 + wid;   // [0, (NC-1)*DI)
  int c = __builtin_amdgcn_readfirstlane(pair / DI);
  int d = __builtin_amdgcn_readfirstlane(pair - (pair / DI) * DI);
  float A = -__expf(A_log[(size_t)d * DS + lane]);
  int l0 = c * TC;
  float dtv = dt[(size_t)(l0 + lane) * DI + d];   // lane t -> dt_{l0+t}
  float xv  = xc[(size_t)(l0 + lane) * DI + d];
  const float* pB = xdbl + (size_t)l0 * NXD + DR + lane;
  float s = 0.f;
#pragma unroll 8
  for (int t = 0; t < TC; ++t) {
    float dt_c = lane_read(dtv, t);
    float x_c  = lane_read(xv, t);
    float B_c  = pB[(size_t)t * NXD];
    float dA = __expf(dt_c * A);
    s = fmaf(dA, s, dt_c * x_c * B_c);
  }
  // dsum = sum over chunk of dt: one butterfly over the preloaded vector
  float dsum = dtv;
  int a0 = (lane ^ 1) << 2, a1 = (lane ^ 2) << 2, a2 = (lane ^ 4) << 2;
  int a3 = (lane ^ 8) << 2, a4 = (lane ^ 16) << 2, a5 = (lane ^ 32) << 2;
  dsum = bp_add(dsum, a0); dsum = bp_add(dsum, a1); dsum = bp_add(dsum, a2);
  dsum = bp_add(dsum, a3); dsum = bp_add(dsum, a4); dsum = bp_add(dsum, a5);
  send[((size_t)c * DI + d) * DS + lane] = s;
  if (lane == 0) dts[c * DI + d] = dsum;
}

// ---------------------------------------------------------------------------
// Pass 2: prefix over chunks. s_init[c] = exp(A*dts[c-1])*s_init[c-1]+send[c-1]
// ---------------------------------------------------------------------------
__global__ __launch_bounds__(256) void scan_p2(const float* __restrict__ send,
                                               const float* __restrict__ dts,
                                               const float* __restrict__ A_log,
                                               float* __restrict__ sinit) {
  int lane = threadIdx.x & 63;
  int wid = threadIdx.x >> 6;
  int d = __builtin_amdgcn_readfirstlane(blockIdx.x * 4 + wid);
  float A = -__expf(A_log[(size_t)d * DS + lane]);
  float s = 0.f;
  for (int c = 1; c < NC; ++c) {
    float P = __expf(A * dts[(c - 1) * DI + d]);
    s = fmaf(P, s, send[((size_t)(c - 1) * DI + d) * DS + lane]);
    sinit[((size_t)c * DI + d) * DS + lane] = s;
  }
}

// ---------------------------------------------------------------------------
// Pass 3: re-run each chunk from its true initial state. All-lane butterfly
// gives every lane the n-sum; lane t keeps step t's value (cndmask), so the
// silu(z)/D epilogue runs once per chunk, fully parallel & using the
// preloaded z/x lane-vectors.
// ---------------------------------------------------------------------------
__global__ __launch_bounds__(256) void scan_p3(const float* __restrict__ dt,
                                               const float* __restrict__ xc,
                                               const float* __restrict__ xdbl,
                                               const float* __restrict__ A_log,
                                               const float* __restrict__ Dv,
                                               const float* __restrict__ xz,
                                               const float* __restrict__ sinit,
                                               float* __restrict__ y) {
  int lane = threadIdx.x & 63;
  int wid = threadIdx.x >> 6;
  int pair = blockIdx.x * 4 + wid;   // [0, NC*DI)
  int c = __builtin_amdgcn_readfirstlane(pair / DI);
  int d = __builtin_amdgcn_readfirstlane(pair - (pair / DI) * DI);
  float A = -__expf(A_log[(size_t)d * DS + lane]);
  float Dd = Dv[d];
  int l0 = c * TC;
  float dtv = dt[(size_t)(l0 + lane) * DI + d];
  float xv  = xc[(size_t)(l0 + lane) * DI + d];
  float zv  = xz[(size_t)(l0 + lane) * (2 * DI) + DI + d];
  float s = (c == 0) ? 0.f : sinit[((size_t)c * DI + d) * DS + lane];
  const float* pB = xdbl + (size_t)l0 * NXD + DR + lane;
  int a0 = (lane ^ 1) << 2, a1 = (lane ^ 2) << 2, a2 = (lane ^ 4) << 2;
  int a3 = (lane ^ 8) << 2, a4 = (lane ^ 16) << 2, a5 = (lane ^ 32) << 2;
  float yacc = 0.f;
#pragma unroll 8
  for (int t = 0; t < TC; ++t) {
    float dt_c = lane_read(dtv, t);
    float x_c  = lane_read(xv, t);
    float B_c  = pB[(size_t)t * NXD];
    float C_c  = pB[(size_t)t * NXD + DS];
    float dA = __expf(dt_c * A);
    s = fmaf(dA, s, dt_c * x_c * B_c);
    float p = s * C_c;
    p = bp_add(p, a0); p = bp_add(p, a1); p = bp_add(p, a2);
    p = bp_add(p, a3); p = bp_add(p, a4); p = bp_add(p, a5);
    yacc = (lane == t) ? p : yacc;
  }
  // parallel epilogue: lane t handles l = l0 + t
  float sig = 1.f / (1.f + __expf(-zv));
  y[(size_t)(l0 + lane) * DI + d] = (yacc + xv * Dd) * (zv * sig);
}

// ---------------------------------------------------------------------------
// Launcher. Workspace region R reused by lifetime (stream-ordered).
// ---------------------------------------------------------------------------
extern "C" void kernel_launch(void* const* d_in, const int* in_sizes, int n_in,
                              void* d_out, int out_size, void* d_ws, size_t ws_size,
                              hipStream_t stream) {
  const float* x         = (const float*)d_in[0];
  const float* ln_w      = (const float*)d_in[1];
  const float* ln_b      = (const float*)d_in[2];
  const float* in_proj_w = (const float*)d_in[3];
  const float* conv_w    = (const float*)d_in[4];
  const float* conv_b    = (const float*)d_in[5];
  const float* x_proj_w  = (const float*)d_in[6];
  const float* dt_proj_w = (const float*)d_in[7];
  const float* dt_proj_b = (const float*)d_in[8];
  const float* A_log     = (const float*)d_in[9];
  const float* Dv        = (const float*)d_in[10];
  const float* out_proj_w= (const float*)d_in[11];
  float* out = (float*)d_out;

  float* ws = (float*)d_ws;
  float* h     = ws;                        // 393216
  float* xz    = h + 393216;                // 1572864
  float* xconv = xz + 1572864;              // 786432
  float* xdbl  = xconv + 786432;            // 90112
  float* dtb   = xdbl + 90112;              // 786432
  float* yb    = dtb + 786432;              // 786432
  float* R     = yb + 786432;               // 3145728 shared region
  float* part1 = R;                         // 2*512*3072 = 3145728
  float* part2 = R;                         // 16*512*176 = 1441792
  float* send  = R;                         // 7*1536*64  = 688128
  float* dts   = R + 688128;                // 7*1536     = 10752
  float* sinit = R + 698880;                // 8*1536*64  = 786432
  float* part3 = R;                         // 8*512*768  = 3145728

  // 1. LayerNorm
  ln_kernel<<<L_SEQ, 256, 0, stream>>>(x, ln_w, ln_b, h);

  // 2. in_proj (split-K 2)
  gemm_tiled<<<dim3(3072 / BN, L_SEQ / BM, 2), 256, 0, stream>>>(
      h, in_proj_w, part1, L_SEQ, 2 * DI, DM);
  reduce_add<<<(L_SEQ * 2 * DI + 255) / 256, 256, 0, stream>>>(
      part1, L_SEQ * 2 * DI, 2, nullptr, xz);

  // 3. causal depthwise conv + SiLU
  conv_silu_kernel<<<(L_SEQ * DI) / 256, 256, 0, stream>>>(xz, conv_w, conv_b, xconv);

  // 4. x_proj (split-K 16)
  gemm_tiled<<<dim3((NXD + BN - 1) / BN, L_SEQ / BM, 16), 256, 0, stream>>>(
      xconv, x_proj_w, part2, L_SEQ, NXD, DI);
  reduce_add<<<(L_SEQ * NXD + 255) / 256, 256, 0, stream>>>(
      part2, L_SEQ * NXD, 16, nullptr, xdbl);

  // 5. dt_proj + softplus
  dtproj_kernel<<<(L_SEQ * DI) / 256, 256, 0, stream>>>(xdbl, dt_proj_w, dt_proj_b, dtb);

  // 6. chunked selective scan
  scan_p1<<<((NC - 1) * DI) / 4, 256, 0, stream>>>(dtb, xconv, xdbl, A_log, send, dts);
  scan_p2<<<DI / 4, 256, 0, stream>>>(send, dts, A_log, sinit);
  scan_p3<<<(NC * DI) / 4, 256, 0, stream>>>(dtb, xconv, xdbl, A_log, Dv, xz, sinit, yb);

  // 7. out_proj + residual (split-K 8)
  gemm_tiled<<<dim3(DM / BN, L_SEQ / BM, 8), 256, 0, stream>>>(
      yb, out_proj_w, part3, L_SEQ, DM, DI);
  reduce_add<<<(L_SEQ * DM + 255) / 256, 256, 0, stream>>>(
      part3, L_SEQ * DM, 8, x, out);
}

// Round 4
// 263.506 us; speedup vs baseline: 2.0867x; 1.0655x over previous
//
#include <hip/hip_runtime.h>
#include <hip/hip_bf16.h>
#include <math.h>

#define L_SEQ 512
#define DM 768
#define DI 1536
#define DS 64
#define DC 4
#define DR 48
#define NXD 176  // DR + 2*DS
#define NC 8     // time chunks
#define TC 64    // steps per chunk

typedef __attribute__((ext_vector_type(8))) short short8;
typedef __attribute__((ext_vector_type(4))) float float4v;

// ---------------------------------------------------------------------------
// helpers
// ---------------------------------------------------------------------------
__device__ __forceinline__ float bp_add(float p, int addr) {
  return p + __int_as_float(__builtin_amdgcn_ds_bpermute(addr, __float_as_int(p)));
}
__device__ __forceinline__ float lane_read(float v, int t) {
  return __int_as_float(__builtin_amdgcn_readlane(__float_as_int(v), t));
}
__device__ __forceinline__ short f2bf(float v) {
  __hip_bfloat16 h = __float2bfloat16(v);
  return *reinterpret_cast<short*>(&h);
}

// ---------------------------------------------------------------------------
// LayerNorm -> bf16 h (consumed only by the in_proj MFMA GEMM)
// ---------------------------------------------------------------------------
__global__ __launch_bounds__(256) void ln_kernel(const float* __restrict__ x,
                                                 const float* __restrict__ w,
                                                 const float* __restrict__ b,
                                                 short* __restrict__ h) {
  int l = blockIdx.x;
  int tid = threadIdx.x;
  const float* xr = x + l * DM;
  float s = 0.f, s2 = 0.f;
  for (int i = tid; i < DM; i += 256) { float t = xr[i]; s += t; s2 += t * t; }
#pragma unroll
  for (int off = 32; off; off >>= 1) { s += __shfl_xor(s, off); s2 += __shfl_xor(s2, off); }
  __shared__ float ls[4], ls2[4];
  int wid = tid >> 6, lane = tid & 63;
  if (lane == 0) { ls[wid] = s; ls2[wid] = s2; }
  __syncthreads();
  s = ls[0] + ls[1] + ls[2] + ls[3];
  s2 = ls2[0] + ls2[1] + ls2[2] + ls2[3];
  float mean = s * (1.f / DM);
  float var = s2 * (1.f / DM) - mean * mean;
  float rstd = rsqrtf(var + 1e-5f);
  for (int i = tid; i < DM; i += 256)
    h[l * DM + i] = f2bf((xr[i] - mean) * rstd * w[i] + b[i]);
}

// ---------------------------------------------------------------------------
// f32 -> bf16 weight conversion (all three projection weights, one launch)
// ---------------------------------------------------------------------------
#define NWI (2 * DI * DM)   // 2359296
#define NWX (NXD * DI)      // 270336
#define NWO (DM * DI)       // 1179648
__global__ __launch_bounds__(256) void cvt_weights(const float* __restrict__ wi, short* __restrict__ wio,
                                                   const float* __restrict__ wx, short* __restrict__ wxo,
                                                   const float* __restrict__ wo, short* __restrict__ woo) {
  int i = blockIdx.x * 256 + threadIdx.x;
  if (i < NWI) wio[i] = f2bf(wi[i]);
  if (i < NWX) wxo[i] = f2bf(wx[i]);
  if (i < NWO) woo[i] = f2bf(wo[i]);
}

// ---------------------------------------------------------------------------
// bf16 MFMA GEMM: C[M,N] = A[M,K] . B[N,K]^T (+ optional f32 residual).
// Direct-from-global fragments (A/W are L2-resident at these sizes):
//   A-operand: lane holds A[m=lane&15][k=(lane>>4)*8+j] -> one 16B load
//   B-operand: lane holds B[n=lane&15][k=(lane>>4)*8+j] -> one 16B load
//   C/D:       col=lane&15, row=(lane>>4)*4+reg
// Block = 4 waves; tile 64m x 64n; wave w covers n-cols [bx*64+w*16, +16),
// 4 m-tiles of 16. M%64==0, K%32==0 required; N guarded (x_proj N=176).
// ---------------------------------------------------------------------------
__global__ __launch_bounds__(256) void gemm_bf16(const short* __restrict__ A,
                                                 const short* __restrict__ B,
                                                 float* __restrict__ C,
                                                 int N, int K,
                                                 const float* __restrict__ res) {
  int lane = threadIdx.x & 63;
  int w = threadIdx.x >> 6;
  int m_base = blockIdx.y * 64;
  int n0 = blockIdx.x * 64 + w * 16;
  int fr = lane & 15;
  int koff = (lane >> 4) * 8;
  int nrow = n0 + fr; if (nrow > N - 1) nrow = N - 1;  // clamp; cols guarded at store
  const short* pB = B + (size_t)nrow * K + koff;
  const short* pA = A + (size_t)(m_base + fr) * K + koff;
  float4v acc[4];
#pragma unroll
  for (int mt = 0; mt < 4; ++mt) acc[mt] = (float4v){0.f, 0.f, 0.f, 0.f};
#pragma unroll 4
  for (int k0 = 0; k0 < K; k0 += 32) {
    short8 bf = *(const short8*)(pB + k0);
    short8 a0 = *(const short8*)(pA + k0);
    short8 a1 = *(const short8*)(pA + (size_t)16 * K + k0);
    short8 a2 = *(const short8*)(pA + (size_t)32 * K + k0);
    short8 a3 = *(const short8*)(pA + (size_t)48 * K + k0);
    acc[0] = __builtin_amdgcn_mfma_f32_16x16x32_bf16(a0, bf, acc[0], 0, 0, 0);
    acc[1] = __builtin_amdgcn_mfma_f32_16x16x32_bf16(a1, bf, acc[1], 0, 0, 0);
    acc[2] = __builtin_amdgcn_mfma_f32_16x16x32_bf16(a2, bf, acc[2], 0, 0, 0);
    acc[3] = __builtin_amdgcn_mfma_f32_16x16x32_bf16(a3, bf, acc[3], 0, 0, 0);
  }
  int col = n0 + (lane & 15);
  if (col < N) {
    int rbase = m_base + (lane >> 4) * 4;
#pragma unroll
    for (int mt = 0; mt < 4; ++mt) {
#pragma unroll
      for (int r = 0; r < 4; ++r) {
        int m = rbase + mt * 16 + r;
        float v = acc[mt][r];
        if (res) v += res[(size_t)m * N + col];
        C[(size_t)m * N + col] = v;
      }
    }
  }
}

// ---------------------------------------------------------------------------
// Causal depthwise conv (window 4) + bias + SiLU; dual store f32 + bf16
// ---------------------------------------------------------------------------
__global__ __launch_bounds__(256) void conv_silu_kernel(const float* __restrict__ xz,
                                                        const float* __restrict__ cw,
                                                        const float* __restrict__ cb,
                                                        float* __restrict__ xc,
                                                        short* __restrict__ xcb) {
  int idx = blockIdx.x * 256 + threadIdx.x;
  if (idx >= L_SEQ * DI) return;
  int l = idx / DI, d = idx - l * DI;
  float acc = cb[d];
#pragma unroll
  for (int j = 0; j < DC; ++j) {
    int ll = l - (DC - 1) + j;
    if (ll >= 0) acc = fmaf(xz[(size_t)ll * (2 * DI) + d], cw[d * DC + j], acc);
  }
  float sig = 1.f / (1.f + __expf(-acc));
  float v = acc * sig;
  xc[idx] = v;
  xcb[idx] = f2bf(v);
}

// ---------------------------------------------------------------------------
// dt = softplus(x_dbl[:, :DR] @ dt_proj_w^T + dt_proj_b)
// ---------------------------------------------------------------------------
__global__ __launch_bounds__(256) void dtproj_kernel(const float* __restrict__ xdbl,
                                                     const float* __restrict__ w,
                                                     const float* __restrict__ bias,
                                                     float* __restrict__ dt) {
  int idx = blockIdx.x * 256 + threadIdx.x;
  if (idx >= L_SEQ * DI) return;
  int l = idx / DI, d = idx - l * DI;
  const float* xr = xdbl + (size_t)l * NXD;
  const float* wr = w + (size_t)d * DR;
  float acc = bias[d];
#pragma unroll 8
  for (int r = 0; r < DR; ++r) acc = fmaf(xr[r], wr[r], acc);
  dt[idx] = (acc > 20.f) ? acc : log1pf(__expf(acc));
}

// ---------------------------------------------------------------------------
// Scan pass 1 (chunks 0..NC-2): local recurrence from 0; emit end state + sum(dt)
// ---------------------------------------------------------------------------
__global__ __launch_bounds__(256) void scan_p1(const float* __restrict__ dt,
                                               const float* __restrict__ xc,
                                               const float* __restrict__ xdbl,
                                               const float* __restrict__ A_log,
                                               float* __restrict__ send,
                                               float* __restrict__ dts) {
  int lane = threadIdx.x & 63;
  int wid = threadIdx.x >> 6;
  int pair = blockIdx.x * 4 + wid;
  int c = __builtin_amdgcn_readfirstlane(pair / DI);
  int d = __builtin_amdgcn_readfirstlane(pair - (pair / DI) * DI);
  float A = -__expf(A_log[(size_t)d * DS + lane]);
  int l0 = c * TC;
  float dtv = dt[(size_t)(l0 + lane) * DI + d];
  float xv  = xc[(size_t)(l0 + lane) * DI + d];
  const float* pB = xdbl + (size_t)l0 * NXD + DR + lane;
  float s = 0.f;
#pragma unroll 8
  for (int t = 0; t < TC; ++t) {
    float dt_c = lane_read(dtv, t);
    float x_c  = lane_read(xv, t);
    float B_c  = pB[(size_t)t * NXD];
    float dA = __expf(dt_c * A);
    s = fmaf(dA, s, dt_c * x_c * B_c);
  }
  float dsum = dtv;
  dsum = bp_add(dsum, (lane ^ 1) << 2);  dsum = bp_add(dsum, (lane ^ 2) << 2);
  dsum = bp_add(dsum, (lane ^ 4) << 2);  dsum = bp_add(dsum, (lane ^ 8) << 2);
  dsum = bp_add(dsum, (lane ^ 16) << 2); dsum = bp_add(dsum, (lane ^ 32) << 2);
  send[((size_t)c * DI + d) * DS + lane] = s;
  if (lane == 0) dts[c * DI + d] = dsum;
}

// ---------------------------------------------------------------------------
// Scan pass 2: prefix over chunks
// ---------------------------------------------------------------------------
__global__ __launch_bounds__(256) void scan_p2(const float* __restrict__ send,
                                               const float* __restrict__ dts,
                                               const float* __restrict__ A_log,
                                               float* __restrict__ sinit) {
  int lane = threadIdx.x & 63;
  int wid = threadIdx.x >> 6;
  int d = __builtin_amdgcn_readfirstlane(blockIdx.x * 4 + wid);
  float A = -__expf(A_log[(size_t)d * DS + lane]);
  float s = 0.f;
  for (int c = 1; c < NC; ++c) {
    float P = __expf(A * dts[(c - 1) * DI + d]);
    s = fmaf(P, s, send[((size_t)(c - 1) * DI + d) * DS + lane]);
    sinit[((size_t)c * DI + d) * DS + lane] = s;
  }
}

// ---------------------------------------------------------------------------
// Scan pass 3: recurrence from true init state. n-reduction batched through
// LDS: keep P[j]=s*C in regs for 16 steps, flush with 16 ds_write_b32
// (conflict-free) + 8 ds_read_b64 per lane (pad-66 stride -> 2-way, free)
// + 3 bpermutes. ~1.4 DS-ops/step vs 6 bpermutes/step before.
// Emits y as bf16 for the out_proj MFMA GEMM.
// ---------------------------------------------------------------------------
__global__ __launch_bounds__(256) void scan_p3(const float* __restrict__ dt,
                                               const float* __restrict__ xc,
                                               const float* __restrict__ xdbl,
                                               const float* __restrict__ A_log,
                                               const float* __restrict__ Dv,
                                               const float* __restrict__ xz,
                                               const float* __restrict__ sinit,
                                               short* __restrict__ y) {
  __shared__ float Pb[4][16][66];
  int lane = threadIdx.x & 63;
  int wid = threadIdx.x >> 6;
  int pair = blockIdx.x * 4 + wid;
  int c = __builtin_amdgcn_readfirstlane(pair / DI);
  int d = __builtin_amdgcn_readfirstlane(pair - (pair / DI) * DI);
  float A = -__expf(A_log[(size_t)d * DS + lane]);
  float Dd = Dv[d];
  int l0 = c * TC;
  float dtv = dt[(size_t)(l0 + lane) * DI + d];
  float xv  = xc[(size_t)(l0 + lane) * DI + d];
  float zv  = xz[(size_t)(l0 + lane) * (2 * DI) + DI + d];
  float s = (c == 0) ? 0.f : sinit[((size_t)c * DI + d) * DS + lane];
  const float* pB = xdbl + (size_t)l0 * NXD + DR + lane;
  float yv = 0.f;
#pragma unroll
  for (int sb = 0; sb < 4; ++sb) {
    float P[16];
#pragma unroll
    for (int j = 0; j < 16; ++j) {
      int t = sb * 16 + j;
      float dt_c = lane_read(dtv, t);
      float x_c  = lane_read(xv, t);
      float B_c  = pB[(size_t)t * NXD];
      float C_c  = pB[(size_t)t * NXD + DS];
      float dA = __expf(dt_c * A);
      s = fmaf(dA, s, dt_c * x_c * B_c);
      P[j] = s * C_c;
    }
#pragma unroll
    for (int j = 0; j < 16; ++j) Pb[wid][j][lane] = P[j];
    // reduce rows: 4 lanes per row t4; each lane sums a 16-float quarter
    int t4 = lane >> 2, q = lane & 3;
    const float* row = &Pb[wid][t4][q * 16];
    float part = 0.f;
#pragma unroll
    for (int k = 0; k < 8; ++k) {
      float2 v2 = *(const float2*)(row + 2 * k);
      part += v2.x + v2.y;
    }
    part = bp_add(part, (lane ^ 1) << 2);
    part = bp_add(part, (lane ^ 2) << 2);
    // route: lane L (sb-th 16-group) takes row (L&15) from source lane (L&15)*4
    float got = __int_as_float(
        __builtin_amdgcn_ds_bpermute((lane & 15) << 4, __float_as_int(part)));
    yv = ((lane >> 4) == sb) ? got : yv;
  }
  float sig = 1.f / (1.f + __expf(-zv));
  y[(size_t)(l0 + lane) * DI + d] = f2bf((yv + xv * Dd) * (zv * sig));
}

// ---------------------------------------------------------------------------
// Launcher
// ---------------------------------------------------------------------------
extern "C" void kernel_launch(void* const* d_in, const int* in_sizes, int n_in,
                              void* d_out, int out_size, void* d_ws, size_t ws_size,
                              hipStream_t stream) {
  const float* x         = (const float*)d_in[0];
  const float* ln_w      = (const float*)d_in[1];
  const float* ln_b      = (const float*)d_in[2];
  const float* in_proj_w = (const float*)d_in[3];
  const float* conv_w    = (const float*)d_in[4];
  const float* conv_b    = (const float*)d_in[5];
  const float* x_proj_w  = (const float*)d_in[6];
  const float* dt_proj_w = (const float*)d_in[7];
  const float* dt_proj_b = (const float*)d_in[8];
  const float* A_log     = (const float*)d_in[9];
  const float* Dv        = (const float*)d_in[10];
  const float* out_proj_w= (const float*)d_in[11];
  float* out = (float*)d_out;

  float* ws = (float*)d_ws;
  // f32 buffers
  float* xz    = ws;                        // 512*3072 = 1572864
  float* xconv = xz + 1572864;              // 786432
  float* xdbl  = xconv + 786432;            // 90112
  float* dtb   = xdbl + 90112;              // 786432
  float* send  = dtb + 786432;              // 7*1536*64 = 688128
  float* dts   = send + 688128;             // 10752
  float* sinit = dts + 10752;               // 786432
  float* fend  = sinit + 786432;
  // bf16 buffers (short), carved after the f32 region
  short* sbase = (short*)fend;
  short* h_bf  = sbase;                     // 393216
  short* wi_bf = h_bf + 393216;             // 2359296
  short* wx_bf = wi_bf + NWI;               // 270336
  short* wo_bf = wx_bf + NWX;               // 1179648
  short* xc_bf = wo_bf + NWO;               // 786432
  short* y_bf  = xc_bf + 786432;            // 786432

  // 0. weight conversion (f32 -> bf16)
  cvt_weights<<<NWI / 256, 256, 0, stream>>>(in_proj_w, wi_bf, x_proj_w, wx_bf,
                                             out_proj_w, wo_bf);
  // 1. LayerNorm -> bf16
  ln_kernel<<<L_SEQ, 256, 0, stream>>>(x, ln_w, ln_b, h_bf);

  // 2. in_proj: xz[512,3072] = h . Wi^T
  gemm_bf16<<<dim3(3072 / 64, L_SEQ / 64), 256, 0, stream>>>(
      h_bf, wi_bf, xz, 2 * DI, DM, nullptr);

  // 3. conv + SiLU (f32 + bf16 stores)
  conv_silu_kernel<<<(L_SEQ * DI) / 256, 256, 0, stream>>>(xz, conv_w, conv_b,
                                                           xconv, xc_bf);

  // 4. x_proj: xdbl[512,176] = xconv . Wx^T
  gemm_bf16<<<dim3((NXD + 63) / 64, L_SEQ / 64), 256, 0, stream>>>(
      xc_bf, wx_bf, xdbl, NXD, DI, nullptr);

  // 5. dt_proj + softplus
  dtproj_kernel<<<(L_SEQ * DI) / 256, 256, 0, stream>>>(xdbl, dt_proj_w, dt_proj_b, dtb);

  // 6. chunked selective scan
  scan_p1<<<((NC - 1) * DI) / 4, 256, 0, stream>>>(dtb, xconv, xdbl, A_log, send, dts);
  scan_p2<<<DI / 4, 256, 0, stream>>>(send, dts, A_log, sinit);
  scan_p3<<<(NC * DI) / 4, 256, 0, stream>>>(dtb, xconv, xdbl, A_log, Dv, xz, sinit, y_bf);

  // 7. out_proj + residual: out = x + y . Wo^T
  gemm_bf16<<<dim3(DM / 64, L_SEQ / 64), 256, 0, stream>>>(
      y_bf, wo_bf, out, DM, DI, x);
}